// Round 1
// baseline (284.497 us; speedup 1.0000x reference)
//
#include <hip/hip_runtime.h>
#include <hip/hip_bf16.h>
#include <math.h>

// Problem dims (fixed by reference)
constexpr int Bn = 8, Sn = 1024, Fn = 32, Dn = 128, Cc = 16;
constexpr int NSITE = Bn * Sn;

#define ALPHA_HALF 5.0f   // alpha * 0.5
#define EPSV 1e-8f

// ---------------------------------------------------------------------------
// Kernel 1: normalize cluster centers Cj [16,128] -> Cn in workspace
// ---------------------------------------------------------------------------
__global__ void normC_kernel(const float* __restrict__ Cj, float* __restrict__ CnOut) {
    int c = blockIdx.x;       // 16 blocks
    int d = threadIdx.x;      // 128 threads
    float v = Cj[c * Dn + d];
    float sq = v * v;
    #pragma unroll
    for (int off = 32; off > 0; off >>= 1) sq += __shfl_down(sq, off);
    __shared__ float part[2];
    if ((threadIdx.x & 63) == 0) part[threadIdx.x >> 6] = sq;
    __syncthreads();
    float nrm = sqrtf(part[0] + part[1]);
    CnOut[c * Dn + d] = v / fmaxf(nrm, EPSV);
}

// ---------------------------------------------------------------------------
// Kernel 2: one block per (b,s) site. 256 threads = 4 waves.
// ---------------------------------------------------------------------------
__launch_bounds__(256)
__global__ void site_kernel(const float* __restrict__ Hs,
                            const float* __restrict__ CnIn,
                            const float* __restrict__ W,
                            const float* __restrict__ bvec,
                            const float* __restrict__ imp_in,
                            float* __restrict__ f_out,
                            float* __restrict__ imp_out) {
    __shared__ __align__(16) float sH[32][132];   // Hs tile, +4 pad
    __shared__ __align__(16) float sC[16][132];   // normalized centers
    __shared__ __align__(16) float sFt[32][132];  // F_tj = relu(Hs@W^T+b)
    __shared__ float sCos[32][17];                // cosine sims (17: conflict-free row reads)
    __shared__ float sW3[32][16];                 // softmax over centers
    __shared__ __align__(16) float sWg[32][16];   // softmax over features
    __shared__ float sInv[32];                    // 1/max(||Hs_f||,eps)
    __shared__ float sImp[32];

    const int tid = threadIdx.x;
    const int site = blockIdx.x;
    const float* hsrc = Hs + (size_t)site * (Fn * Dn);

    // ---- Phase 0: stage tiles (coalesced float4) ----
    #pragma unroll
    for (int i = 0; i < 4; ++i) {
        int idx = tid + i * 256;          // float4 index, 1024 total
        int row = idx >> 5;               // 32 float4 per row
        int col4 = idx & 31;
        float4 v = ((const float4*)hsrc)[idx];
        *(float4*)&sH[row][col4 * 4] = v;
    }
    #pragma unroll
    for (int i = 0; i < 2; ++i) {
        int idx = tid + i * 256;          // 512 total
        int row = idx >> 5;
        int col4 = idx & 31;
        float4 v = ((const float4*)CnIn)[idx];
        *(float4*)&sC[row][col4 * 4] = v;
    }
    if (tid < 32) sImp[tid] = imp_in[(size_t)site * Fn + tid];
    __syncthreads();

    // ---- Phase 1: row inverse norms (8 lanes per row) ----
    {
        int g = tid >> 3, l8 = tid & 7;
        float sq = 0.f;
        #pragma unroll
        for (int i = 0; i < 4; ++i) {
            float4 h = *(const float4*)&sH[g][l8 * 4 + 32 * i];
            sq += h.x * h.x + h.y * h.y + h.z * h.z + h.w * h.w;
        }
        sq += __shfl_xor(sq, 1);
        sq += __shfl_xor(sq, 2);
        sq += __shfl_xor(sq, 4);
        if (l8 == 0) sInv[g] = 1.0f / fmaxf(sqrtf(sq), EPSV);
    }
    __syncthreads();

    // ---- Phase 2: cos[f][c] (512 dot products, 2 per thread) ----
    #pragma unroll
    for (int pp = 0; pp < 2; ++pp) {
        int p = tid + pp * 256;
        int f = p >> 4, c = p & 15;
        float dot = 0.f;
        #pragma unroll 8
        for (int j = 0; j < 32; ++j) {
            float4 h  = *(const float4*)&sH[f][4 * j];
            float4 cc = *(const float4*)&sC[c][4 * j];
            dot += h.x * cc.x + h.y * cc.y + h.z * cc.z + h.w * cc.w;
        }
        sCos[f][c] = dot * sInv[f];
    }
    __syncthreads();

    // ---- Phase 3: two softmaxes (tiny) ----
    if (tid < 32) {
        // w3: softmax over centers (per feature row)
        int f = tid;
        float l[16]; float m = -1e30f;
        #pragma unroll
        for (int c = 0; c < 16; ++c) { l[c] = -ALPHA_HALF * (1.0f - sCos[f][c]); m = fmaxf(m, l[c]); }
        float s = 0.f;
        #pragma unroll
        for (int c = 0; c < 16; ++c) { l[c] = __expf(l[c] - m); s += l[c]; }
        float inv = 1.0f / s;
        #pragma unroll
        for (int c = 0; c < 16; ++c) sW3[f][c] = l[c] * inv;
    } else if (tid >= 64 && tid < 80) {
        // w: softmax over features (per center column)
        int c = tid - 64;
        float l[32]; float m = -1e30f;
        #pragma unroll
        for (int f = 0; f < 32; ++f) { l[f] = -ALPHA_HALF * (1.0f - sCos[f][c]); m = fmaxf(m, l[f]); }
        float s = 0.f;
        #pragma unroll
        for (int f = 0; f < 32; ++f) { l[f] = __expf(l[f] - m); s += l[f]; }
        float inv = 1.0f / s;
        #pragma unroll
        for (int f = 0; f < 32; ++f) sWg[f][c] = l[f] * inv;
    }
    __syncthreads();

    // ---- Phase 4a: importance output (threads 0..15, same wave that wrote sW3) ----
    if (tid < 16) {
        int c = tid;
        float raw = 0.f;
        #pragma unroll
        for (int f = 0; f < 32; ++f) raw += sW3[f][c] * sImp[f];
        float m = raw;
        #pragma unroll
        for (int off = 8; off > 0; off >>= 1) m = fmaxf(m, __shfl_xor(m, off));
        float e = __expf(raw - m);
        float s = e;
        #pragma unroll
        for (int off = 8; off > 0; off >>= 1) s += __shfl_xor(s, off);
        imp_out[(size_t)site * Cc + c] = e / s;
    }

    // ---- Phase 4b: F_tj = relu(Hs @ W^T + b) -> LDS ----
    // thread: 2 output dims (d0,d0+1) x 8 features (f0..f0+7); W rows L1/L2-resident
    {
        int lane = tid & 63, wv = tid >> 6;
        int d0 = lane * 2, f0 = wv * 8;
        float acc0[8] = {0, 0, 0, 0, 0, 0, 0, 0};
        float acc1[8] = {0, 0, 0, 0, 0, 0, 0, 0};
        const float4* w0 = (const float4*)(W + d0 * Dn);
        const float4* w1 = (const float4*)(W + (d0 + 1) * Dn);
        #pragma unroll 2
        for (int j = 0; j < 32; ++j) {
            float4 a = w0[j];
            float4 bq = w1[j];
            #pragma unroll
            for (int k = 0; k < 8; ++k) {
                float4 h = *(const float4*)&sH[f0 + k][4 * j];
                acc0[k] += h.x * a.x + h.y * a.y + h.z * a.z + h.w * a.w;
                acc1[k] += h.x * bq.x + h.y * bq.y + h.z * bq.z + h.w * bq.w;
            }
        }
        float b0 = bvec[d0], b1 = bvec[d0 + 1];
        #pragma unroll
        for (int k = 0; k < 8; ++k) {
            sFt[f0 + k][d0]     = fmaxf(acc0[k] + b0, 0.f);
            sFt[f0 + k][d0 + 1] = fmaxf(acc1[k] + b1, 0.f);
        }
    }
    __syncthreads();

    // ---- Phase 5: f_t_new[c][d] = sum_f w[f][c] * F_tj[f][d] ----
    {
        int d = tid & 127, ch = tid >> 7;
        int c0 = ch * 8;
        float acc[8] = {0, 0, 0, 0, 0, 0, 0, 0};
        for (int f = 0; f < 32; ++f) {
            float ft = sFt[f][d];
            float4 wA = *(const float4*)&sWg[f][c0];
            float4 wB = *(const float4*)&sWg[f][c0 + 4];
            acc[0] += wA.x * ft; acc[1] += wA.y * ft; acc[2] += wA.z * ft; acc[3] += wA.w * ft;
            acc[4] += wB.x * ft; acc[5] += wB.y * ft; acc[6] += wB.z * ft; acc[7] += wB.w * ft;
        }
        float* outp = f_out + (size_t)site * (Cc * Dn);
        #pragma unroll
        for (int k = 0; k < 8; ++k) outp[(c0 + k) * Dn + d] = acc[k];
    }
}

// ---------------------------------------------------------------------------
extern "C" void kernel_launch(void* const* d_in, const int* in_sizes, int n_in,
                              void* d_out, int out_size, void* d_ws, size_t ws_size,
                              hipStream_t stream) {
    const float* Hs  = (const float*)d_in[0];
    const float* Cj  = (const float*)d_in[1];
    const float* W   = (const float*)d_in[2];
    const float* b   = (const float*)d_in[3];
    const float* imp = (const float*)d_in[4];

    float* f_out   = (float*)d_out;                          // [B,S,C,D]
    float* imp_out = f_out + (size_t)NSITE * Cc * Dn;        // [B,S,C]
    float* CnBuf   = (float*)d_ws;                           // [C,D] normalized centers

    hipLaunchKernelGGL(normC_kernel, dim3(Cc), dim3(Dn), 0, stream, Cj, CnBuf);
    hipLaunchKernelGGL(site_kernel, dim3(NSITE), dim3(256), 0, stream,
                       Hs, CnBuf, W, b, imp, f_out, imp_out);
}

// Round 2
// 69.368 us; speedup vs baseline: 4.1013x; 4.1013x over previous
//
#include <hip/hip_runtime.h>
#include <hip/hip_bf16.h>
#include <math.h>

// Problem dims (fixed by reference)
constexpr int Bn = 8, Sn = 1024, Fn = 32, Dn = 128, Cc = 16;
constexpr int NSITE = Bn * Sn;

#define EPSV 1e-8f

typedef __attribute__((ext_vector_type(8))) short bf16x8;
typedef __attribute__((ext_vector_type(4))) short bf16x4;
typedef __attribute__((ext_vector_type(4))) float f32x4;

__device__ inline short f2bf(float x) {
    __hip_bfloat16 h = __float2bfloat16(x);   // RNE
    short s;
    __builtin_memcpy(&s, &h, sizeof(s));
    return s;
}

__device__ inline bf16x8 cvt8(float4 x0, float4 x1) {
    bf16x8 r;
    r[0] = f2bf(x0.x); r[1] = f2bf(x0.y); r[2] = f2bf(x0.z); r[3] = f2bf(x0.w);
    r[4] = f2bf(x1.x); r[5] = f2bf(x1.y); r[6] = f2bf(x1.z); r[7] = f2bf(x1.w);
    return r;
}

// ---------------------------------------------------------------------------
// Kernel 1: normalize cluster centers Cj [16,128] -> fp32 Cn in workspace
// ---------------------------------------------------------------------------
__global__ void normC_kernel(const float* __restrict__ Cj, float* __restrict__ CnOut) {
    int c = blockIdx.x;       // 16 blocks
    int d = threadIdx.x;      // 128 threads
    float v = Cj[c * Dn + d];
    float sq = v * v;
    #pragma unroll
    for (int off = 32; off > 0; off >>= 1) sq += __shfl_down(sq, off);
    __shared__ float part[2];
    if ((threadIdx.x & 63) == 0) part[threadIdx.x >> 6] = sq;
    __syncthreads();
    float nrm = sqrtf(part[0] + part[1]);
    CnOut[c * Dn + d] = v / fmaxf(nrm, EPSV);
}

// ---------------------------------------------------------------------------
// Kernel 2: pack W [128(out),128(in)] fp32 -> bf16 MFMA B-fragment layout.
// B[k][n] = W[n][k]; frag id = (n>>4)*4 + (k>>5); lane = ((k>>3)&3)*16 + (n&15);
// j = k&7.  Wb[(frag*64 + lane)*8 + j]
// ---------------------------------------------------------------------------
__global__ void packW_kernel(const float* __restrict__ W, short* __restrict__ Wb) {
    int t = blockIdx.x * 256 + threadIdx.x;   // 16384
    int n = t >> 7, k = t & 127;
    short v = f2bf(W[n * Dn + k]);
    int frag = (n >> 4) * 4 + (k >> 5);
    int lane = ((k >> 3) & 3) * 16 + (n & 15);
    int j = k & 7;
    Wb[(frag * 64 + lane) * 8 + j] = v;
}

// ---------------------------------------------------------------------------
// Kernel 3: one block per (b,s) site. 256 threads = 4 waves. MFMA everywhere.
// ---------------------------------------------------------------------------
__launch_bounds__(256)
__global__ void site_kernel(const float* __restrict__ Hs,
                            const float* __restrict__ CnBuf,
                            const short* __restrict__ Wb,
                            const float* __restrict__ bvec,
                            const float* __restrict__ imp_in,
                            float* __restrict__ f_out,
                            float* __restrict__ imp_out) {
    __shared__ __align__(16) short sHb[32][136];    // Hs bf16 (136 = 128+8, 272B rows)
    __shared__ __align__(16) short F_tjT[128][48];  // F_tj transposed: [dim][feature]
    __shared__ float sWg[32][17];                   // softmax-over-features weights
    __shared__ float sInv[32];                      // 1/max(||Hs_f||,eps)

    const int tid  = threadIdx.x;
    const int site = blockIdx.x;
    const int w    = tid >> 6;       // wave 0..3
    const int lane = tid & 63;
    const int c16  = lane & 15;
    const int g    = lane >> 4;

    // ---- Phase 0: stage Hs -> bf16 LDS, fused fp32 row norms ----
    {
        const float* hsrc = Hs + (size_t)site * (Fn * Dn);
        int r = tid >> 3;            // row 0..31
        int q = tid & 7;             // 16-float segment within row
        const float4* s4 = (const float4*)(hsrc + r * Dn + q * 16);
        float4 x0 = s4[0], x1 = s4[1], x2 = s4[2], x3 = s4[3];
        float sq = x0.x*x0.x + x0.y*x0.y + x0.z*x0.z + x0.w*x0.w
                 + x1.x*x1.x + x1.y*x1.y + x1.z*x1.z + x1.w*x1.w
                 + x2.x*x2.x + x2.y*x2.y + x2.z*x2.z + x2.w*x2.w
                 + x3.x*x3.x + x3.y*x3.y + x3.z*x3.z + x3.w*x3.w;
        sq += __shfl_xor(sq, 1);
        sq += __shfl_xor(sq, 2);
        sq += __shfl_xor(sq, 4);
        if (q == 0) sInv[r] = 1.0f / fmaxf(sqrtf(sq), EPSV);
        *(bf16x8*)&sHb[r][q * 16]     = cvt8(x0, x1);
        *(bf16x8*)&sHb[r][q * 16 + 8] = cvt8(x2, x3);
    }
    __syncthreads();

    // ---- Phase 1: Linear via MFMA (all waves) + cosine MFMA (wave 0) ----
    f32x4 zro = {0.f, 0.f, 0.f, 0.f};
    f32x4 acc00 = zro, acc01 = zro, acc10 = zro, acc11 = zro;
    f32x4 cos0 = zro, cos1 = zro;

    #pragma unroll
    for (int kt = 0; kt < 4; ++kt) {
        bf16x8 a0 = *(const bf16x8*)&sHb[c16][kt * 32 + g * 8];
        bf16x8 a1 = *(const bf16x8*)&sHb[16 + c16][kt * 32 + g * 8];
        // W fragments: nt=0 frag = 8w+kt ; nt=1 frag = 8w+4+kt
        bf16x8 b0 = *(const bf16x8*)&Wb[((w * 8) + kt) * 512 + lane * 8];
        bf16x8 b1 = *(const bf16x8*)&Wb[((w * 8) + 4 + kt) * 512 + lane * 8];
        acc00 = __builtin_amdgcn_mfma_f32_16x16x32_bf16(a0, b0, acc00, 0, 0, 0);
        acc01 = __builtin_amdgcn_mfma_f32_16x16x32_bf16(a0, b1, acc01, 0, 0, 0);
        acc10 = __builtin_amdgcn_mfma_f32_16x16x32_bf16(a1, b0, acc10, 0, 0, 0);
        acc11 = __builtin_amdgcn_mfma_f32_16x16x32_bf16(a1, b1, acc11, 0, 0, 0);
        if (w == 0) {
            const float* cp = CnBuf + c16 * Dn + kt * 32 + g * 8;
            bf16x8 bc = cvt8(*(const float4*)cp, *(const float4*)(cp + 4));
            cos0 = __builtin_amdgcn_mfma_f32_16x16x32_bf16(a0, bc, cos0, 0, 0, 0);
            cos1 = __builtin_amdgcn_mfma_f32_16x16x32_bf16(a1, bc, cos1, 0, 0, 0);
        }
    }

    // ---- Phase 2 (wave 0): softmaxes fully in-register + importance ----
    if (w == 0) {
        // lane holds cos[f][c16] for f = {4g+r, 16+4g+r}, r=0..3 (C-layout)
        float s0[4], s1[4];
        #pragma unroll
        for (int r = 0; r < 4; ++r) {
            s0[r] = 5.0f * cos0[r] * sInv[4 * g + r];        // logits + const (cancels)
            s1[r] = 5.0f * cos1[r] * sInv[16 + 4 * g + r];
        }
        // w: softmax over features f (in-lane 8 values, then xor16/xor32 over g)
        float m = s0[0];
        #pragma unroll
        for (int r = 0; r < 4; ++r) { m = fmaxf(m, s0[r]); m = fmaxf(m, s1[r]); }
        m = fmaxf(m, __shfl_xor(m, 16));
        m = fmaxf(m, __shfl_xor(m, 32));
        float e0[4], e1[4], sum = 0.f;
        #pragma unroll
        for (int r = 0; r < 4; ++r) {
            e0[r] = __expf(s0[r] - m); e1[r] = __expf(s1[r] - m);
            sum += e0[r] + e1[r];
        }
        sum += __shfl_xor(sum, 16);
        sum += __shfl_xor(sum, 32);
        float inv = 1.0f / sum;
        #pragma unroll
        for (int r = 0; r < 4; ++r) {
            sWg[4 * g + r][c16]      = e0[r] * inv;
            sWg[16 + 4 * g + r][c16] = e1[r] * inv;
        }
        // w3: softmax over centers c per feature f (xor 1,2,4,8), fused with
        // importance contraction  imp_raw[c] = sum_f w3[f][c] * imp[f]
        const float* impp = imp_in + (size_t)site * Fn;
        float t = 0.f;
        #pragma unroll
        for (int h = 0; h < 2; ++h) {
            #pragma unroll
            for (int r = 0; r < 4; ++r) {
                float sv = h ? s1[r] : s0[r];
                float m3 = sv;
                m3 = fmaxf(m3, __shfl_xor(m3, 1));
                m3 = fmaxf(m3, __shfl_xor(m3, 2));
                m3 = fmaxf(m3, __shfl_xor(m3, 4));
                m3 = fmaxf(m3, __shfl_xor(m3, 8));
                float e3 = __expf(sv - m3);
                float q3 = e3;
                q3 += __shfl_xor(q3, 1);
                q3 += __shfl_xor(q3, 2);
                q3 += __shfl_xor(q3, 4);
                q3 += __shfl_xor(q3, 8);
                t += (e3 / q3) * impp[h * 16 + 4 * g + r];
            }
        }
        t += __shfl_xor(t, 16);
        t += __shfl_xor(t, 32);
        // softmax over c, write imp_out
        float mi = t;
        mi = fmaxf(mi, __shfl_xor(mi, 1));
        mi = fmaxf(mi, __shfl_xor(mi, 2));
        mi = fmaxf(mi, __shfl_xor(mi, 4));
        mi = fmaxf(mi, __shfl_xor(mi, 8));
        float ei = __expf(t - mi);
        float si = ei;
        si += __shfl_xor(si, 1);
        si += __shfl_xor(si, 2);
        si += __shfl_xor(si, 4);
        si += __shfl_xor(si, 8);
        if (g == 0) imp_out[(size_t)site * Cc + c16] = ei / si;
    }

    // ---- Phase 3: bias + relu + store F_tj transposed (bf16) to LDS ----
    {
        float bias0 = bvec[32 * w + c16];
        float bias1 = bvec[32 * w + 16 + c16];
        #pragma unroll
        for (int mt = 0; mt < 2; ++mt) {
            #pragma unroll
            for (int nt = 0; nt < 2; ++nt) {
                f32x4 v = (mt == 0) ? (nt == 0 ? acc00 : acc01)
                                    : (nt == 0 ? acc10 : acc11);
                float bb = nt ? bias1 : bias0;
                bf16x4 pk;
                #pragma unroll
                for (int r = 0; r < 4; ++r) pk[r] = f2bf(fmaxf(v[r] + bb, 0.f));
                int row = 32 * w + 16 * nt + c16;       // output dim n
                *(bf16x4*)&F_tjT[row][16 * mt + 4 * g] = pk;   // cols = features
            }
        }
    }
    __syncthreads();

    // ---- Phase 4: f_t_new[c][n] = sum_f w[f][c] * F_tj[f][n] via MFMA ----
    {
        bf16x8 wA;
        #pragma unroll
        for (int j = 0; j < 8; ++j) wA[j] = f2bf(sWg[8 * g + j][c16]);
        float* op = f_out + (size_t)site * (Cc * Dn);
        #pragma unroll
        for (int nt = 0; nt < 2; ++nt) {
            int n = 32 * w + 16 * nt + c16;
            bf16x8 bF = *(const bf16x8*)&F_tjT[n][8 * g];
            f32x4 r = __builtin_amdgcn_mfma_f32_16x16x32_bf16(wA, bF, zro, 0, 0, 0);
            #pragma unroll
            for (int jj = 0; jj < 4; ++jj)
                op[(4 * g + jj) * Dn + n] = r[jj];
        }
    }
}

// ---------------------------------------------------------------------------
extern "C" void kernel_launch(void* const* d_in, const int* in_sizes, int n_in,
                              void* d_out, int out_size, void* d_ws, size_t ws_size,
                              hipStream_t stream) {
    const float* Hs  = (const float*)d_in[0];
    const float* Cj  = (const float*)d_in[1];
    const float* W   = (const float*)d_in[2];
    const float* b   = (const float*)d_in[3];
    const float* imp = (const float*)d_in[4];

    float* f_out   = (float*)d_out;                          // [B,S,C,D]
    float* imp_out = f_out + (size_t)NSITE * Cc * Dn;        // [B,S,C]

    float* CnBuf = (float*)d_ws;                             // [16,128] fp32
    short* Wb    = (short*)((char*)d_ws + 16 * Dn * sizeof(float)); // bf16 frags, 32KB

    hipLaunchKernelGGL(normC_kernel, dim3(Cc), dim3(Dn), 0, stream, Cj, CnBuf);
    hipLaunchKernelGGL(packW_kernel, dim3((Dn * Dn) / 256), dim3(256), 0, stream, W, Wb);
    hipLaunchKernelGGL(site_kernel, dim3(NSITE), dim3(256), 0, stream,
                       Hs, CnBuf, Wb, b, imp, f_out, imp_out);
}